// Round 2
// baseline (629.011 us; speedup 1.0000x reference)
//
#include <hip/hip_runtime.h>
#include <cmath>

#define VOCAB 50257

// fast tanh: 1 - 2/(e^{2x}+1).  ~5 VALU instrs vs ~40 for libm tanhf.
__device__ __forceinline__ float fast_tanh(float x) {
    float e = __expf(2.0f * x);                  // v_mul + v_exp_f32
    float r = __builtin_amdgcn_rcpf(e + 1.0f);   // v_rcp_f32
    return fmaf(-2.0f, r, 1.0f);
}

// ---------------------------------------------------------------------------
// Kernel A: emb_proj[v][j] = sum_k emb[v][k] * W_top[k][j]   (W_top = W_ih[0:128])
// ---------------------------------------------------------------------------
__global__ __launch_bounds__(256) void emb_proj_kernel(
    const float* __restrict__ emb, const float* __restrict__ W_ih,
    float* __restrict__ emb_proj)
{
    __shared__ __align__(16) float Ws[128 * 128];
    __shared__ __align__(16) float As[64][129];
    const int t  = threadIdx.x;
    const int v0 = blockIdx.x * 64;

    for (int i = t; i < 4096; i += 256)
        ((float4*)Ws)[i] = ((const float4*)W_ih)[i];
    for (int i = t; i < 64 * 128; i += 256) {
        int r = i >> 7, k = i & 127;
        int v = v0 + r;
        As[r][k] = (v < VOCAB) ? emb[(size_t)v * 128 + k] : 0.0f;
    }
    __syncthreads();

    const int j0 = (t & 31) * 4;
    const int r0 = (t >> 5) * 8;
    float4 acc[8];
#pragma unroll
    for (int i = 0; i < 8; ++i) acc[i] = make_float4(0.f, 0.f, 0.f, 0.f);

#pragma unroll 4
    for (int k = 0; k < 128; ++k) {
        float4 w = *(const float4*)&Ws[k * 128 + j0];
#pragma unroll
        for (int i = 0; i < 8; ++i) {
            float a = As[r0 + i][k];
            acc[i].x = fmaf(a, w.x, acc[i].x);
            acc[i].y = fmaf(a, w.y, acc[i].y);
            acc[i].z = fmaf(a, w.z, acc[i].z);
            acc[i].w = fmaf(a, w.w, acc[i].w);
        }
    }
#pragma unroll
    for (int i = 0; i < 8; ++i) {
        int v = v0 + r0 + i;
        if (v < VOCAB)
            *(float4*)&emb_proj[(size_t)v * 128 + j0] = acc[i];
    }
}

// ---------------------------------------------------------------------------
// Kernel B: persistent RNN. 256 blocks x 256 threads, 16 rows/block.
// Column-split waves: wave w owns output cols [32w,32w+32); lane (c=l&7,
// rp=l>>3) computes rows {2rp,2rp+1} x cols [32w+4c, +4).  Per-k unique LDS
// w-traffic = 128B/wave (vs 512B unsplit) -> VALU-bound, not LDS-bound.
// hT double-buffered -> 1 barrier/step.
// ---------------------------------------------------------------------------
__global__ __launch_bounds__(256) void rnn_kernel(
    const int* __restrict__ x, const int* __restrict__ tc,
    const float* __restrict__ tgt_emb,
    const float* __restrict__ W_ih, const float* __restrict__ W_hh,
    const float* __restrict__ b_ih, const float* __restrict__ b_hh,
    const float* __restrict__ W_cls, const float* __restrict__ b_cls,
    const float* __restrict__ emb_proj, float* __restrict__ out)
{
    __shared__ __align__(16) float Ws[128 * 128];   // 64 KB weight buffer
    __shared__ __align__(16) float hA[128 * 18];    // h transposed [k][r], pad 18
    __shared__ __align__(16) float hB[128 * 18];    // double buffer
    __shared__ int xs[16 * 128];

    const int t    = threadIdx.x;
    const int rb0  = blockIdx.x * 16;
    const int wave = t >> 6;
    const int lane = t & 63;
    const int c    = lane & 7;
    const int r0   = (lane >> 3) * 2;        // rows r0, r0+1
    const int j0   = wave * 32 + c * 4;      // 4 output cols

    // ---- stage x rows, W_bot, target embeddings (transposed into hB) ----
    for (int i = t; i < 2048; i += 256)
        xs[i] = x[(size_t)rb0 * 128 + i];
    for (int i = t; i < 4096; i += 256)
        ((float4*)Ws)[i] = ((const float4*)W_ih)[4096 + i];   // W_bot rows 128..255
    for (int i = t; i < 2048; i += 256) {
        int r = i >> 7, k = i & 127;
        hB[k * 18 + r] = tgt_emb[(size_t)tc[rb0 + r] * 128 + k];
    }
    __syncthreads();

    // ---- phase 1: C = tgt @ W_bot + b_ih + b_hh ----
    float4 c0 = make_float4(0.f, 0.f, 0.f, 0.f), c1 = c0;
#pragma unroll 8
    for (int k = 0; k < 128; ++k) {
        float4 w = *(const float4*)&Ws[k * 128 + j0];
        float2 h = *(const float2*)&hB[k * 18 + r0];
        c0.x = fmaf(h.x, w.x, c0.x); c0.y = fmaf(h.x, w.y, c0.y);
        c0.z = fmaf(h.x, w.z, c0.z); c0.w = fmaf(h.x, w.w, c0.w);
        c1.x = fmaf(h.y, w.x, c1.x); c1.y = fmaf(h.y, w.y, c1.y);
        c1.z = fmaf(h.y, w.z, c1.z); c1.w = fmaf(h.y, w.w, c1.w);
    }
    {
        float4 bi = *(const float4*)&b_ih[j0];
        float4 bh = *(const float4*)&b_hh[j0];
        c0.x += bi.x + bh.x; c0.y += bi.y + bh.y;
        c0.z += bi.z + bh.z; c0.w += bi.w + bh.w;
        c1.x += bi.x + bh.x; c1.y += bi.y + bh.y;
        c1.z += bi.z + bh.z; c1.w += bi.w + bh.w;
    }
    __syncthreads();   // done reading Ws(W_bot) and hB(tgt)

    // ---- stage W_hh, zero hA ----
    for (int i = t; i < 4096; i += 256)
        ((float4*)Ws)[i] = ((const float4*)W_hh)[i];
    for (int i = t; i < 128 * 18; i += 256) hA[i] = 0.0f;
    __syncthreads();

    // ---- phase 2: 128-step recurrence, 1 barrier/step ----
    float* cur = hA;
    float* nxt = hB;
    float4 u0 = *(const float4*)&emb_proj[(size_t)xs[r0 * 128] * 128 + j0];
    float4 u1 = *(const float4*)&emb_proj[(size_t)xs[(r0 + 1) * 128] * 128 + j0];

    for (int step = 0; step < 128; ++step) {
        float4 n0 = u0, n1 = u1;
        if (step < 127) {   // prefetch next step's gather (hidden under k-loop)
            n0 = *(const float4*)&emb_proj[(size_t)xs[r0 * 128 + step + 1] * 128 + j0];
            n1 = *(const float4*)&emb_proj[(size_t)xs[(r0 + 1) * 128 + step + 1] * 128 + j0];
        }
        float4 a0 = c0, a1 = c1;
#pragma unroll 8
        for (int k = 0; k < 128; ++k) {
            float4 w = *(const float4*)&Ws[k * 128 + j0];
            float2 h = *(const float2*)&cur[k * 18 + r0];
            a0.x = fmaf(h.x, w.x, a0.x); a0.y = fmaf(h.x, w.y, a0.y);
            a0.z = fmaf(h.x, w.z, a0.z); a0.w = fmaf(h.x, w.w, a0.w);
            a1.x = fmaf(h.y, w.x, a1.x); a1.y = fmaf(h.y, w.y, a1.y);
            a1.z = fmaf(h.y, w.z, a1.z); a1.w = fmaf(h.y, w.w, a1.w);
        }
        a0.x += u0.x; a0.y += u0.y; a0.z += u0.z; a0.w += u0.w;
        a1.x += u1.x; a1.y += u1.y; a1.z += u1.z; a1.w += u1.w;

        float t00 = fast_tanh(a0.x), t01 = fast_tanh(a0.y);
        float t02 = fast_tanh(a0.z), t03 = fast_tanh(a0.w);
        float t10 = fast_tanh(a1.x), t11 = fast_tanh(a1.y);
        float t12 = fast_tanh(a1.z), t13 = fast_tanh(a1.w);

        // write transposed into nxt (cur untouched -> no pre-write barrier)
        *(float2*)&nxt[(j0 + 0) * 18 + r0] = make_float2(t00, t10);
        *(float2*)&nxt[(j0 + 1) * 18 + r0] = make_float2(t01, t11);
        *(float2*)&nxt[(j0 + 2) * 18 + r0] = make_float2(t02, t12);
        *(float2*)&nxt[(j0 + 3) * 18 + r0] = make_float2(t03, t13);
        __syncthreads();

        float* tmp = cur; cur = nxt; nxt = tmp;
        u0 = n0; u1 = n1;
    }
    // h_last now in `cur` (128 steps -> back to hA)

    // ---- phase 3: logits + softmax (simple row-in-half-wave mapping) ----
    for (int i = t; i < 4096; i += 256)
        ((float4*)Ws)[i] = ((const float4*)W_cls)[i];
    __syncthreads();

    const int j0o = (t & 31) * 4;
    const int r0o = (t >> 5) * 2;
    float4 l0 = make_float4(0.f, 0.f, 0.f, 0.f), l1 = l0;
#pragma unroll 8
    for (int k = 0; k < 128; ++k) {
        float4 w = *(const float4*)&Ws[k * 128 + j0o];
        float2 h = *(const float2*)&cur[k * 18 + r0o];
        l0.x = fmaf(h.x, w.x, l0.x); l0.y = fmaf(h.x, w.y, l0.y);
        l0.z = fmaf(h.x, w.z, l0.z); l0.w = fmaf(h.x, w.w, l0.w);
        l1.x = fmaf(h.y, w.x, l1.x); l1.y = fmaf(h.y, w.y, l1.y);
        l1.z = fmaf(h.y, w.z, l1.z); l1.w = fmaf(h.y, w.w, l1.w);
    }
    {
        float4 bc = *(const float4*)&b_cls[j0o];
        l0.x += bc.x; l0.y += bc.y; l0.z += bc.z; l0.w += bc.w;
        l1.x += bc.x; l1.y += bc.y; l1.z += bc.z; l1.w += bc.w;
    }

    float m0 = fmaxf(fmaxf(l0.x, l0.y), fmaxf(l0.z, l0.w));
    float m1 = fmaxf(fmaxf(l1.x, l1.y), fmaxf(l1.z, l1.w));
#pragma unroll
    for (int m = 16; m >= 1; m >>= 1) {
        m0 = fmaxf(m0, __shfl_xor(m0, m, 64));
        m1 = fmaxf(m1, __shfl_xor(m1, m, 64));
    }
    l0.x = __expf(l0.x - m0); l0.y = __expf(l0.y - m0);
    l0.z = __expf(l0.z - m0); l0.w = __expf(l0.w - m0);
    l1.x = __expf(l1.x - m1); l1.y = __expf(l1.y - m1);
    l1.z = __expf(l1.z - m1); l1.w = __expf(l1.w - m1);
    float s0 = l0.x + l0.y + l0.z + l0.w;
    float s1 = l1.x + l1.y + l1.z + l1.w;
#pragma unroll
    for (int m = 16; m >= 1; m >>= 1) {
        s0 += __shfl_xor(s0, m, 64);
        s1 += __shfl_xor(s1, m, 64);
    }
    float i0 = 1.0f / s0, i1 = 1.0f / s1;
    l0.x *= i0; l0.y *= i0; l0.z *= i0; l0.w *= i0;
    l1.x *= i1; l1.y *= i1; l1.z *= i1; l1.w *= i1;

    const int row0 = rb0 + r0o;
    *(float4*)&out[(size_t)row0 * 128 + j0o]       = l0;
    *(float4*)&out[(size_t)(row0 + 1) * 128 + j0o] = l1;
}

// ---------------------------------------------------------------------------
extern "C" void kernel_launch(void* const* d_in, const int* in_sizes, int n_in,
                              void* d_out, int out_size, void* d_ws, size_t ws_size,
                              hipStream_t stream)
{
    const int*   x     = (const int*)d_in[0];
    const int*   tc    = (const int*)d_in[1];
    const float* emb   = (const float*)d_in[2];
    const float* tgt   = (const float*)d_in[3];
    const float* W_ih  = (const float*)d_in[4];
    const float* W_hh  = (const float*)d_in[5];
    const float* b_ih  = (const float*)d_in[6];
    const float* b_hh  = (const float*)d_in[7];
    const float* W_cls = (const float*)d_in[8];
    const float* b_cls = (const float*)d_in[9];
    float* out = (float*)d_out;
    float* emb_proj = (float*)d_ws;   // 50257*128 floats = 25.7 MB scratch

    emb_proj_kernel<<<(VOCAB + 63) / 64, 256, 0, stream>>>(emb, W_ih, emb_proj);
    rnn_kernel<<<4096 / 16, 256, 0, stream>>>(x, tc, tgt, W_ih, W_hh,
                                              b_ih, b_hh, W_cls, b_cls,
                                              emb_proj, out);
}

// Round 3
// 250.750 us; speedup vs baseline: 2.5085x; 2.5085x over previous
//
#include <hip/hip_runtime.h>
#include <cmath>

#define VOCAB 50257
#define LDH   140                 // fp32 h row stride (bank-clean for b128 reads)
#define SCL   2048.0f             // lo-term scaling (avoids f16 denormal flush)
#define ISCL  (1.0f / 2048.0f)

typedef _Float16 half8 __attribute__((ext_vector_type(8)));
typedef float    f32x4 __attribute__((ext_vector_type(4)));

// fast tanh: 1 - 2/(e^{2x}+1)
__device__ __forceinline__ float fast_tanh(float x) {
    float e = __expf(2.0f * x);
    float r = __builtin_amdgcn_rcpf(e + 1.0f);
    return fmaf(-2.0f, r, 1.0f);
}

// Split fp32 -> (hi, lo*2048) fp16 pair.
__device__ __forceinline__ void splitf(float v, _Float16& hi, _Float16& lo) {
    hi = (_Float16)v;
    lo = (_Float16)((v - (float)hi) * SCL);
}

// Load B-fragments (K=128 x NT*16 cols) of a row-major [128][128] fp32 matrix
// from global, split into hi / scaled-lo fp16 fragments.
// Lane l: n = n0 + nt*16 + (l&15), k = kc*32 + (l>>4)*8 + i.
template <int NT>
__device__ __forceinline__ void load_b_frags(const float* __restrict__ W,
        int n0, int g, int ln, half8 (&bHi)[NT][4], half8 (&bLo)[NT][4])
{
#pragma unroll
    for (int nt = 0; nt < NT; ++nt) {
        const int n = n0 + nt * 16 + ln;
#pragma unroll
        for (int kc = 0; kc < 4; ++kc) {
            const int kb = kc * 32 + g * 8;
            half8 hv, lv;
#pragma unroll
            for (int i = 0; i < 8; ++i) {
                float w = W[(size_t)(kb + i) * 128 + n];
                _Float16 hi, lo; splitf(w, hi, lo);
                hv[i] = hi; lv[i] = lo;
            }
            bHi[nt][kc] = hv; bLo[nt][kc] = lv;
        }
    }
}

// Read A-fragments (16 x 128 fp32 tile in LDS, row stride LDH) and split.
// Lane l: m = l&15, k = kc*32 + (l>>4)*8 + i.
__device__ __forceinline__ void read_a_frags(const float* __restrict__ hb,
        int ln, int g, half8 (&aHi)[4], half8 (&aLo)[4])
{
    const float* base = hb + ln * LDH + g * 8;
    float4 ra[4][2];
#pragma unroll
    for (int kc = 0; kc < 4; ++kc) {
        ra[kc][0] = *(const float4*)(base + kc * 32);
        ra[kc][1] = *(const float4*)(base + kc * 32 + 4);
    }
#pragma unroll
    for (int kc = 0; kc < 4; ++kc) {
        const float* rp = (const float*)&ra[kc][0];
        half8 hv, lv;
#pragma unroll
        for (int i = 0; i < 8; ++i) {
            _Float16 hi, lo; splitf(rp[i], hi, lo);
            hv[i] = hi; lv[i] = lo;
        }
        aHi[kc] = hv; aLo[kc] = lv;
    }
}

// accA += aHi*bHi ; accB += aHi*bLo' + aLo'*bHi   (result = accA + accB/2048)
__device__ __forceinline__ void mfma3(half8 aH, half8 aL, half8 bH, half8 bL,
                                      f32x4& accA, f32x4& accB)
{
    accA = __builtin_amdgcn_mfma_f32_16x16x32_f16(aH, bH, accA, 0, 0, 0);
    accB = __builtin_amdgcn_mfma_f32_16x16x32_f16(aH, bL, accB, 0, 0, 0);
    accB = __builtin_amdgcn_mfma_f32_16x16x32_f16(aL, bH, accB, 0, 0, 0);
}

// ---------------------------------------------------------------------------
// Kernel A: emb_proj = emb @ W_top  (M=50257, N=128, K=128), MFMA split-fp16.
// 256 persistent blocks, 32 vocab rows per iter, 7 iters. Waves: 2 row-groups
// x 2 col-groups(64). W fragments live in registers for the whole kernel.
// ---------------------------------------------------------------------------
__global__ __launch_bounds__(256) void emb_proj_mfma(
    const float* __restrict__ emb, const float* __restrict__ W_ih,
    float* __restrict__ emb_proj)
{
    __shared__ __align__(16) float As[32 * LDH];
    const int t = threadIdx.x;
    const int w = t >> 6, lane = t & 63, g = lane >> 4, ln = lane & 15;
    const int wr = w >> 1, wc = w & 1;
    const int n0 = wc * 64;

    half8 bHi[4][4], bLo[4][4];
    load_b_frags<4>(W_ih, n0, g, ln, bHi, bLo);   // W_top = rows 0..127

    for (int it = 0; it < 7; ++it) {
        const int vb = blockIdx.x * 32 + it * 8192;
        __syncthreads();                          // prev-iter readers done
        for (int i = t; i < 32 * 128; i += 256) {
            int m = i >> 7, k = i & 127;
            int v = vb + m;
            As[m * LDH + k] = (v < VOCAB) ? emb[(size_t)v * 128 + k] : 0.0f;
        }
        __syncthreads();

        half8 aHi[4], aLo[4];
        read_a_frags(As + wr * 16 * LDH, ln, g, aHi, aLo);
        f32x4 accA[4], accB[4];
#pragma unroll
        for (int nt = 0; nt < 4; ++nt) {
            accA[nt] = {0.f, 0.f, 0.f, 0.f};
            accB[nt] = {0.f, 0.f, 0.f, 0.f};
        }
#pragma unroll
        for (int nt = 0; nt < 4; ++nt)
#pragma unroll
            for (int kc = 0; kc < 4; ++kc)
                mfma3(aHi[kc], aLo[kc], bHi[nt][kc], bLo[nt][kc],
                      accA[nt], accB[nt]);
#pragma unroll
        for (int nt = 0; nt < 4; ++nt)
#pragma unroll
            for (int r = 0; r < 4; ++r) {
                int v = vb + wr * 16 + 4 * g + r;
                if (v < VOCAB)
                    emb_proj[(size_t)v * 128 + n0 + nt * 16 + ln] =
                        accA[nt][r] + accB[nt][r] * ISCL;
            }
    }
}

// ---------------------------------------------------------------------------
// Kernel B: persistent RNN, MFMA split-fp16. 256 blocks x 256 thr, 16 rows.
// Wave w owns N-cols [32w,32w+32) with W_hh B-fragments in registers.
// Per step per wave: 8 ds_read_b128 (A) + 1 b128 (tokens) + 8 b32 writes.
// ---------------------------------------------------------------------------
__global__ __launch_bounds__(256) void rnn_mfma(
    const int* __restrict__ x, const int* __restrict__ tc,
    const float* __restrict__ tgt_emb,
    const float* __restrict__ W_ih, const float* __restrict__ W_hh,
    const float* __restrict__ b_ih, const float* __restrict__ b_hh,
    const float* __restrict__ W_cls, const float* __restrict__ b_cls,
    const float* __restrict__ emb_proj, float* __restrict__ out)
{
    __shared__ __align__(16) float hbuf[2][16 * LDH];   // fp32 h, dbuf
    __shared__ __align__(16) int   xsT[128 * 16];       // tokens [s][m]
    __shared__ float red[2][64];                        // softmax partials

    const int t = threadIdx.x;
    const int w = t >> 6, lane = t & 63, g = lane >> 4, ln = lane & 15;
    const int n0 = w * 32;
    const int rb0 = blockIdx.x * 16;
    const int nA = n0 + ln, nB = n0 + 16 + ln;
    const int mrow = 4 * g;

    // ---- stage tgt rows (fp32) into hbuf[0]; tokens transposed into xsT ----
    for (int i = t; i < 2048; i += 256) {
        int m = i >> 7, k = i & 127;
        hbuf[0][m * LDH + k] = tgt_emb[(size_t)tc[rb0 + m] * 128 + k];
    }
    for (int i = t; i < 2048; i += 256) {
        int m = i >> 7, s = i & 127;
        xsT[s * 16 + m] = x[(size_t)(rb0 + m) * 128 + s];
    }
    __syncthreads();

    // ---- c = tgt @ W_bot + b_ih + b_hh  (one-time MFMA) ----
    half8 bHi[2][4], bLo[2][4];
    load_b_frags<2>(W_ih + 128 * 128, n0, g, ln, bHi, bLo);   // W_bot
    f32x4 c0, c1;
    {
        float bA = b_ih[nA] + b_hh[nA];
        float bB = b_ih[nB] + b_hh[nB];
        f32x4 cA0 = {bA, bA, bA, bA}, cB0 = {0.f, 0.f, 0.f, 0.f};
        f32x4 cA1 = {bB, bB, bB, bB}, cB1 = {0.f, 0.f, 0.f, 0.f};
        half8 aHi[4], aLo[4];
        read_a_frags(hbuf[0], ln, g, aHi, aLo);
#pragma unroll
        for (int kc = 0; kc < 4; ++kc) {
            mfma3(aHi[kc], aLo[kc], bHi[0][kc], bLo[0][kc], cA0, cB0);
            mfma3(aHi[kc], aLo[kc], bHi[1][kc], bLo[1][kc], cA1, cB1);
        }
        c0 = cA0 + cB0 * ISCL;
        c1 = cA1 + cB1 * ISCL;
    }

    // ---- W_hh fragments (resident for all 128 steps) ----
    load_b_frags<2>(W_hh, n0, g, ln, bHi, bLo);

    // ---- u_0 ----
    f32x4 uc0, uc1;
    {
        int4 tk = *(const int4*)&xsT[4 * g];
        int tkr[4] = {tk.x, tk.y, tk.z, tk.w};
#pragma unroll
        for (int r = 0; r < 4; ++r) {
            uc0[r] = emb_proj[(size_t)tkr[r] * 128 + nA];
            uc1[r] = emb_proj[(size_t)tkr[r] * 128 + nB];
        }
    }

    // ---- 128-step recurrence, 1 barrier/step ----
    for (int s = 0; s < 128; ++s) {
        f32x4 accA0 = c0 + uc0, accB0 = {0.f, 0.f, 0.f, 0.f};
        f32x4 accA1 = c1 + uc1, accB1 = {0.f, 0.f, 0.f, 0.f};

        f32x4 un0, un1;                     // prefetch next step's gather
        if (s < 127) {
            int4 tk = *(const int4*)&xsT[(s + 1) * 16 + 4 * g];
            int tkr[4] = {tk.x, tk.y, tk.z, tk.w};
#pragma unroll
            for (int r = 0; r < 4; ++r) {
                un0[r] = emb_proj[(size_t)tkr[r] * 128 + nA];
                un1[r] = emb_proj[(size_t)tkr[r] * 128 + nB];
            }
        }

        if (s > 0) {                        // h_0 = 0: skip MFMA at s=0
            half8 aHi[4], aLo[4];
            read_a_frags(hbuf[s & 1], ln, g, aHi, aLo);
#pragma unroll
            for (int kc = 0; kc < 4; ++kc) {
                mfma3(aHi[kc], aLo[kc], bHi[0][kc], bLo[0][kc], accA0, accB0);
                mfma3(aHi[kc], aLo[kc], bHi[1][kc], bLo[1][kc], accA1, accB1);
            }
        }

        float* nb = hbuf[(s + 1) & 1];
#pragma unroll
        for (int r = 0; r < 4; ++r) {
            nb[(mrow + r) * LDH + nA] = fast_tanh(accA0[r] + accB0[r] * ISCL);
            nb[(mrow + r) * LDH + nB] = fast_tanh(accA1[r] + accB1[r] * ISCL);
        }
        __syncthreads();
        uc0 = un0; uc1 = un1;
    }

    // ---- logits = h_128 @ W_cls + b_cls  (h_128 in hbuf[0]) ----
    load_b_frags<2>(W_cls, n0, g, ln, bHi, bLo);
    f32x4 L0, L1;
    {
        float bA = b_cls[nA], bB = b_cls[nB];
        f32x4 lA0 = {bA, bA, bA, bA}, lB0 = {0.f, 0.f, 0.f, 0.f};
        f32x4 lA1 = {bB, bB, bB, bB}, lB1 = {0.f, 0.f, 0.f, 0.f};
        half8 aHi[4], aLo[4];
        read_a_frags(hbuf[0], ln, g, aHi, aLo);
#pragma unroll
        for (int kc = 0; kc < 4; ++kc) {
            mfma3(aHi[kc], aLo[kc], bHi[0][kc], bLo[0][kc], lA0, lB0);
            mfma3(aHi[kc], aLo[kc], bHi[1][kc], bLo[1][kc], lA1, lB1);
        }
        L0 = lA0 + lB0 * ISCL;
        L1 = lA1 + lB1 * ISCL;
    }

    // ---- softmax over 128 cols (4 waves x 32 cols) ----
    float mx[4];
#pragma unroll
    for (int r = 0; r < 4; ++r) mx[r] = fmaxf(L0[r], L1[r]);
#pragma unroll
    for (int mask = 1; mask <= 8; mask <<= 1)
#pragma unroll
        for (int r = 0; r < 4; ++r)
            mx[r] = fmaxf(mx[r], __shfl_xor(mx[r], mask, 64));
    if (ln == 0)
#pragma unroll
        for (int r = 0; r < 4; ++r) red[0][w * 16 + mrow + r] = mx[r];
    __syncthreads();
    float sm[4];
#pragma unroll
    for (int r = 0; r < 4; ++r) {
        float gm = fmaxf(fmaxf(red[0][mrow + r],      red[0][16 + mrow + r]),
                         fmaxf(red[0][32 + mrow + r], red[0][48 + mrow + r]));
        L0[r] = __expf(L0[r] - gm);
        L1[r] = __expf(L1[r] - gm);
        sm[r] = L0[r] + L1[r];
    }
#pragma unroll
    for (int mask = 1; mask <= 8; mask <<= 1)
#pragma unroll
        for (int r = 0; r < 4; ++r)
            sm[r] += __shfl_xor(sm[r], mask, 64);
    if (ln == 0)
#pragma unroll
        for (int r = 0; r < 4; ++r) red[1][w * 16 + mrow + r] = sm[r];
    __syncthreads();
#pragma unroll
    for (int r = 0; r < 4; ++r) {
        float tot = (red[1][mrow + r]      + red[1][16 + mrow + r]) +
                    (red[1][32 + mrow + r] + red[1][48 + mrow + r]);
        float inv = 1.0f / tot;
        size_t row = (size_t)(rb0 + mrow + r) * 128;
        out[row + nA] = L0[r] * inv;
        out[row + nB] = L1[r] * inv;
    }
}

// ---------------------------------------------------------------------------
extern "C" void kernel_launch(void* const* d_in, const int* in_sizes, int n_in,
                              void* d_out, int out_size, void* d_ws, size_t ws_size,
                              hipStream_t stream)
{
    const int*   x     = (const int*)d_in[0];
    const int*   tc    = (const int*)d_in[1];
    const float* emb   = (const float*)d_in[2];
    const float* tgt   = (const float*)d_in[3];
    const float* W_ih  = (const float*)d_in[4];
    const float* W_hh  = (const float*)d_in[5];
    const float* b_ih  = (const float*)d_in[6];
    const float* b_hh  = (const float*)d_in[7];
    const float* W_cls = (const float*)d_in[8];
    const float* b_cls = (const float*)d_in[9];
    float* out = (float*)d_out;
    float* emb_proj = (float*)d_ws;   // 50257*128 fp32 = 25.7 MB scratch

    emb_proj_mfma<<<256, 256, 0, stream>>>(emb, W_ih, emb_proj);
    rnn_mfma<<<256, 256, 0, stream>>>(x, tc, tgt, W_ih, W_hh,
                                      b_ih, b_hh, W_cls, b_cls,
                                      emb_proj, out);
}

// Round 4
// 226.630 us; speedup vs baseline: 2.7755x; 1.1064x over previous
//
#include <hip/hip_runtime.h>
#include <cmath>

#define VOCAB 50257
#define HSTR  136             // fp16 elems per h row: 272B, 68 dwords (== 4 mod 32 -> 2-way free)
#define SCL   2048.0f
#define ISCL  (1.0f / 2048.0f)

typedef _Float16 half8 __attribute__((ext_vector_type(8)));
typedef _Float16 half4 __attribute__((ext_vector_type(4)));
typedef float    f32x4 __attribute__((ext_vector_type(4)));

// fast tanh: 1 - 2/(e^{2x}+1)
__device__ __forceinline__ float fast_tanh(float x) {
    float e = __expf(2.0f * x);
    float r = __builtin_amdgcn_rcpf(e + 1.0f);
    return fmaf(-2.0f, r, 1.0f);
}
__device__ __forceinline__ void splitf(float v, _Float16& hi, _Float16& lo) {
    hi = (_Float16)v;
    lo = (_Float16)((v - (float)hi) * SCL);
}

// Fragments of a row-major [128][128] fp32 matrix W, used as MFMA operand
// holding W[k][n0+nt*16+ln] at lane l (ln=l&15, g=l>>4), k=kc*32+g*8+i.
// (Serves as B-frag in normal orientation, or A-frag (=W^T) in swapped.)
template <int NT>
__device__ __forceinline__ void load_w_frags(const float* __restrict__ W,
        int n0, int g, int ln, half8 (&wHi)[NT][4], half8 (&wLo)[NT][4])
{
#pragma unroll
    for (int nt = 0; nt < NT; ++nt) {
        const int n = n0 + nt * 16 + ln;
#pragma unroll
        for (int kc = 0; kc < 4; ++kc) {
            const int kb = kc * 32 + g * 8;
            half8 hv, lv;
#pragma unroll
            for (int i = 0; i < 8; ++i) {
                float w = W[(size_t)(kb + i) * 128 + n];
                _Float16 hi, lo; splitf(w, hi, lo);
                hv[i] = hi; lv[i] = lo;
            }
            wHi[nt][kc] = hv; wLo[nt][kc] = lv;
        }
    }
}

// B-frags (h^T): lane l holds h[b=ln][k], k=kc*32+g*8+i -> one b128 per kc.
__device__ __forceinline__ void read_h_frags(const _Float16* __restrict__ hHi,
        const _Float16* __restrict__ hLo, int ln, int g,
        half8 (&bHi)[4], half8 (&bLo)[4])
{
    const int base = ln * HSTR + g * 8;
#pragma unroll
    for (int kc = 0; kc < 4; ++kc) {
        bHi[kc] = *(const half8*)&hHi[base + kc * 32];
        bLo[kc] = *(const half8*)&hLo[base + kc * 32];
    }
}

// accA += aH*bH ; accB += aH*bL + aL*bH  (true = accA + accB/2048)
__device__ __forceinline__ void mfma3(half8 aH, half8 aL, half8 bH, half8 bL,
                                      f32x4& accA, f32x4& accB)
{
    accA = __builtin_amdgcn_mfma_f32_16x16x32_f16(aH, bH, accA, 0, 0, 0);
    accB = __builtin_amdgcn_mfma_f32_16x16x32_f16(aH, bL, accB, 0, 0, 0);
    accB = __builtin_amdgcn_mfma_f32_16x16x32_f16(aL, bH, accB, 0, 0, 0);
}

// ---------------------------------------------------------------------------
// Kernel A: emb_proj = emb @ W_top. 512 blocks (2/CU) x 256 thr, 16 rows/iter,
// 7 iters. W-frags resident in registers; A direct from global w/ prefetch.
// ---------------------------------------------------------------------------
__global__ __launch_bounds__(256, 2) void emb_proj_mfma(
    const float* __restrict__ emb, const float* __restrict__ W_ih,
    float* __restrict__ emb_proj)
{
    const int t = threadIdx.x;
    const int w = t >> 6, lane = t & 63, g = lane >> 4, ln = lane & 15;
    const int n0 = w * 32;

    half8 bHi[2][4], bLo[2][4];
    load_w_frags<2>(W_ih, n0, g, ln, bHi, bLo);   // W_top rows 0..127

    float4 pre[8];
    {
        int row = blockIdx.x * 16 + ln;
        row = row < VOCAB ? row : VOCAB - 1;
        const float* rp = emb + (size_t)row * 128 + g * 8;
#pragma unroll
        for (int kc = 0; kc < 4; ++kc) {
            pre[2 * kc]     = *(const float4*)(rp + kc * 32);
            pre[2 * kc + 1] = *(const float4*)(rp + kc * 32 + 4);
        }
    }

    for (int it = 0; it < 7; ++it) {
        const int vb = it * 8192 + blockIdx.x * 16;
        float4 cur[8];
#pragma unroll
        for (int i = 0; i < 8; ++i) cur[i] = pre[i];
        if (it < 6) {                      // prefetch next iter's A rows
            int row = vb + 8192 + ln;
            row = row < VOCAB ? row : VOCAB - 1;
            const float* rp = emb + (size_t)row * 128 + g * 8;
#pragma unroll
            for (int kc = 0; kc < 4; ++kc) {
                pre[2 * kc]     = *(const float4*)(rp + kc * 32);
                pre[2 * kc + 1] = *(const float4*)(rp + kc * 32 + 4);
            }
        }
        half8 aHi[4], aLo[4];
#pragma unroll
        for (int kc = 0; kc < 4; ++kc) {
            const float* cp = (const float*)&cur[2 * kc];
            half8 hv, lv;
#pragma unroll
            for (int i = 0; i < 8; ++i) {
                _Float16 hi, lo; splitf(cp[i], hi, lo);
                hv[i] = hi; lv[i] = lo;
            }
            aHi[kc] = hv; aLo[kc] = lv;
        }
        f32x4 accA[2], accB[2];
#pragma unroll
        for (int nt = 0; nt < 2; ++nt) {
            accA[nt] = {0.f, 0.f, 0.f, 0.f};
            accB[nt] = {0.f, 0.f, 0.f, 0.f};
        }
#pragma unroll
        for (int nt = 0; nt < 2; ++nt)
#pragma unroll
            for (int kc = 0; kc < 4; ++kc)
                mfma3(aHi[kc], aLo[kc], bHi[nt][kc], bLo[nt][kc],
                      accA[nt], accB[nt]);
#pragma unroll
        for (int nt = 0; nt < 2; ++nt)
#pragma unroll
            for (int r = 0; r < 4; ++r) {
                int v = vb + 4 * g + r;
                if (v < VOCAB)
                    emb_proj[(size_t)v * 128 + n0 + nt * 16 + ln] =
                        accA[nt][r] + accB[nt][r] * ISCL;
            }
    }
}

// ---------------------------------------------------------------------------
// Kernel B: persistent RNN, SWAPPED operands: D[j][b] = W^T . h^T.
// 256 blocks x 256 thr, 16 batch rows/block. Wave w owns j-tiles {2w, 2w+1}
// (A = W^T frags resident). h stored pre-split (hi/lo fp16) as [b][k] in LDS:
// producer writes ds_write_b64, consumer reads ds_read_b128 straight to MFMA.
// ---------------------------------------------------------------------------
__global__ __launch_bounds__(256) void rnn_mfma(
    const int* __restrict__ x, const int* __restrict__ tc,
    const float* __restrict__ tgt_emb,
    const float* __restrict__ W_ih, const float* __restrict__ W_hh,
    const float* __restrict__ b_ih, const float* __restrict__ b_hh,
    const float* __restrict__ W_cls, const float* __restrict__ b_cls,
    const float* __restrict__ emb_proj, float* __restrict__ out)
{
    __shared__ _Float16 sHi[2][16 * HSTR];   // h hi, double-buffered
    __shared__ _Float16 sLo[2][16 * HSTR];   // h lo*2048
    __shared__ int   xsT[128 * 16];          // tokens [s][b]
    __shared__ float red[2][64];             // softmax partials

    const int t = threadIdx.x;
    const int w = t >> 6, lane = t & 63, g = lane >> 4, ln = lane & 15;
    const int rb0 = blockIdx.x * 16;
    const int jg0 = 2 * w;                   // wave's j-tiles: jg0, jg0+1
    const int jc  = 4 * g;                   // j offset within tile (rows 4g..4g+3)

    // ---- stage: tokens [s][b]; tgt rows split into sHi[0]/sLo[0] ----
    for (int i = t; i < 2048; i += 256) {
        int b = i >> 7, s = i & 127;
        xsT[s * 16 + b] = x[(size_t)(rb0 + b) * 128 + s];
    }
    {
        const int b = t >> 4, kb = (t & 15) * 8;
        const int tok = tc[rb0 + b];
        const float* rp = tgt_emb + (size_t)tok * 128 + kb;
        float4 v0 = *(const float4*)rp, v1 = *(const float4*)(rp + 4);
        const float* vp = (const float*)&v0;
        half8 hv, lv;
#pragma unroll
        for (int i = 0; i < 8; ++i) {
            float val = (i < 4) ? vp[i] : ((const float*)&v1)[i - 4];
            _Float16 hi, lo; splitf(val, hi, lo);
            hv[i] = hi; lv[i] = lo;
        }
        *(half8*)&sHi[0][b * HSTR + kb] = hv;
        *(half8*)&sLo[0][b * HSTR + kb] = lv;
    }
    __syncthreads();

    // ---- c[j][b] = (tgt @ W_bot)^T + b_ih + b_hh ----
    half8 wHi[2][4], wLo[2][4];
    load_w_frags<2>(W_ih + 128 * 128, w * 32, g, ln, wHi, wLo);   // W_bot^T
    f32x4 cc[2];
    {
        half8 bH[4], bL[4];
        read_h_frags(sHi[0], sLo[0], ln, g, bH, bL);
        f32x4 cA[2], cB[2];
#pragma unroll
        for (int jt = 0; jt < 2; ++jt) {
            float4 bi = *(const float4*)&b_ih[(jg0 + jt) * 16 + jc];
            float4 bh = *(const float4*)&b_hh[(jg0 + jt) * 16 + jc];
            cA[jt] = {bi.x + bh.x, bi.y + bh.y, bi.z + bh.z, bi.w + bh.w};
            cB[jt] = {0.f, 0.f, 0.f, 0.f};
        }
#pragma unroll
        for (int jt = 0; jt < 2; ++jt)
#pragma unroll
            for (int kc = 0; kc < 4; ++kc)
                mfma3(wHi[jt][kc], wLo[jt][kc], bH[kc], bL[kc], cA[jt], cB[jt]);
#pragma unroll
        for (int jt = 0; jt < 2; ++jt)
#pragma unroll
            for (int r = 0; r < 4; ++r)
                cc[jt][r] = cA[jt][r] + cB[jt][r] * ISCL;
    }

    // ---- W_hh^T fragments, resident for all 128 steps ----
    load_w_frags<2>(W_hh, w * 32, g, ln, wHi, wLo);

    // ---- u_0 (vectorized gather: row tok[b], 4 consecutive j) ----
    f32x4 uc[2];
    {
        const int tok = xsT[0 * 16 + ln];
        const float* up = emb_proj + (size_t)tok * 128 + jc;
#pragma unroll
        for (int jt = 0; jt < 2; ++jt) {
            float4 v = *(const float4*)(up + (jg0 + jt) * 16);
            uc[jt] = {v.x, v.y, v.z, v.w};
        }
    }

    // ---- 128-step recurrence, 1 barrier/step ----
    for (int s = 0; s < 128; ++s) {
        // prefetch next step's u early (latency hides under MFMA)
        f32x4 un[2];
        {
            const int sn = (s < 127) ? s + 1 : s;
            const int tok = xsT[sn * 16 + ln];
            const float* up = emb_proj + (size_t)tok * 128 + jc;
#pragma unroll
            for (int jt = 0; jt < 2; ++jt) {
                float4 v = *(const float4*)(up + (jg0 + jt) * 16);
                un[jt] = {v.x, v.y, v.z, v.w};
            }
        }

        f32x4 accA[2], accB[2];
#pragma unroll
        for (int jt = 0; jt < 2; ++jt) {
            accA[jt] = cc[jt] + uc[jt];
            accB[jt] = {0.f, 0.f, 0.f, 0.f};
        }

        if (s > 0) {                       // h_0 = 0: skip read+MFMA at s=0
            half8 bH[4], bL[4];
            read_h_frags(sHi[s & 1], sLo[s & 1], ln, g, bH, bL);
#pragma unroll
            for (int jt = 0; jt < 2; ++jt)
#pragma unroll
                for (int kc = 0; kc < 4; ++kc)
                    mfma3(wHi[jt][kc], wLo[jt][kc], bH[kc], bL[kc],
                          accA[jt], accB[jt]);
        }

        _Float16* dh = sHi[(s + 1) & 1];
        _Float16* dl = sLo[(s + 1) & 1];
#pragma unroll
        for (int jt = 0; jt < 2; ++jt) {
            half4 hv, lv;
#pragma unroll
            for (int r = 0; r < 4; ++r) {
                float th = fast_tanh(accA[jt][r] + accB[jt][r] * ISCL);
                _Float16 hi, lo; splitf(th, hi, lo);
                hv[r] = hi; lv[r] = lo;
            }
            const int off = ln * HSTR + (jg0 + jt) * 16 + jc;
            *(half4*)&dh[off] = hv;
            *(half4*)&dl[off] = lv;
        }
        __syncthreads();
        uc[0] = un[0]; uc[1] = un[1];
    }
    // h_128 in buffer 0 ((127+1)&1 == 0)

    // ---- logits^T = W_cls^T . h^T + b_cls ----
    load_w_frags<2>(W_cls, w * 32, g, ln, wHi, wLo);
    f32x4 L[2];
    {
        half8 bH[4], bL[4];
        read_h_frags(sHi[0], sLo[0], ln, g, bH, bL);
        f32x4 lA[2], lB[2];
#pragma unroll
        for (int jt = 0; jt < 2; ++jt) {
            float4 bc = *(const float4*)&b_cls[(jg0 + jt) * 16 + jc];
            lA[jt] = {bc.x, bc.y, bc.z, bc.w};
            lB[jt] = {0.f, 0.f, 0.f, 0.f};
        }
#pragma unroll
        for (int jt = 0; jt < 2; ++jt)
#pragma unroll
            for (int kc = 0; kc < 4; ++kc)
                mfma3(wHi[jt][kc], wLo[jt][kc], bH[kc], bL[kc], lA[jt], lB[jt]);
#pragma unroll
        for (int jt = 0; jt < 2; ++jt)
#pragma unroll
            for (int r = 0; r < 4; ++r)
                L[jt][r] = lA[jt][r] + lB[jt][r] * ISCL;
    }

    // ---- softmax over j (128 classes) per batch row b=ln ----
    float mx = L[0][0];
#pragma unroll
    for (int jt = 0; jt < 2; ++jt)
#pragma unroll
        for (int r = 0; r < 4; ++r) mx = fmaxf(mx, L[jt][r]);
    mx = fmaxf(mx, __shfl_xor(mx, 16, 64));
    mx = fmaxf(mx, __shfl_xor(mx, 32, 64));
    if (lane < 16) red[0][w * 16 + ln] = mx;
    __syncthreads();
    const float gm = fmaxf(fmaxf(red[0][ln],      red[0][16 + ln]),
                           fmaxf(red[0][32 + ln], red[0][48 + ln]));
    float sum = 0.f;
#pragma unroll
    for (int jt = 0; jt < 2; ++jt)
#pragma unroll
        for (int r = 0; r < 4; ++r) {
            L[jt][r] = __expf(L[jt][r] - gm);
            sum += L[jt][r];
        }
    sum += __shfl_xor(sum, 16, 64);
    sum += __shfl_xor(sum, 32, 64);
    if (lane < 16) red[1][w * 16 + ln] = sum;
    __syncthreads();
    const float tot = (red[1][ln]      + red[1][16 + ln]) +
                      (red[1][32 + ln] + red[1][48 + ln]);
    const float inv = 1.0f / tot;
#pragma unroll
    for (int jt = 0; jt < 2; ++jt) {
        float4 o = {L[jt][0] * inv, L[jt][1] * inv,
                    L[jt][2] * inv, L[jt][3] * inv};
        *(float4*)&out[(size_t)(rb0 + ln) * 128 + (jg0 + jt) * 16 + jc] = o;
    }
}

// ---------------------------------------------------------------------------
extern "C" void kernel_launch(void* const* d_in, const int* in_sizes, int n_in,
                              void* d_out, int out_size, void* d_ws, size_t ws_size,
                              hipStream_t stream)
{
    const int*   x     = (const int*)d_in[0];
    const int*   tc    = (const int*)d_in[1];
    const float* emb   = (const float*)d_in[2];
    const float* tgt   = (const float*)d_in[3];
    const float* W_ih  = (const float*)d_in[4];
    const float* W_hh  = (const float*)d_in[5];
    const float* b_ih  = (const float*)d_in[6];
    const float* b_hh  = (const float*)d_in[7];
    const float* W_cls = (const float*)d_in[8];
    const float* b_cls = (const float*)d_in[9];
    float* out = (float*)d_out;
    float* emb_proj = (float*)d_ws;   // 50257*128 fp32 = 25.7 MB scratch

    emb_proj_mfma<<<512, 256, 0, stream>>>(emb, W_ih, emb_proj);
    rnn_mfma<<<256, 256, 0, stream>>>(x, tc, tgt, W_ih, W_hh,
                                      b_ih, b_hh, W_cls, b_cls,
                                      emb_proj, out);
}

// Round 6
// 224.976 us; speedup vs baseline: 2.7959x; 1.0074x over previous
//
#include <hip/hip_runtime.h>

#define VOCAB 50257
#define NGRP  3142              // ceil(VOCAB/16)
#define SCL   2048.0f
#define ISCL  (1.0f / 2048.0f)

typedef _Float16 half8 __attribute__((ext_vector_type(8)));
typedef _Float16 half4 __attribute__((ext_vector_type(4)));
typedef float    f32x4 __attribute__((ext_vector_type(4)));

// fast tanh: 1 - 2/(e^{2x}+1)
__device__ __forceinline__ float fast_tanh(float x) {
    float e = __expf(2.0f * x);
    float r = __builtin_amdgcn_rcpf(e + 1.0f);
    return fmaf(-2.0f, r, 1.0f);
}
__device__ __forceinline__ void splitf(float v, _Float16& hi, _Float16& lo) {
    hi = (_Float16)v;
    lo = (_Float16)((v - (float)hi) * SCL);
}

// Fragment slice of a row-major [128][128] fp32 matrix: lane (g,ln) gets
// W[k = kc*32 + g*8 + i][ncol], split into hi / lo*2048 fp16.
__device__ __forceinline__ void load_w4(const float* __restrict__ W,
        int ncol, int g, half8 (&wHi)[4], half8 (&wLo)[4])
{
#pragma unroll
    for (int kc = 0; kc < 4; ++kc) {
        const int kb = kc * 32 + g * 8;
        half8 hv, lv;
#pragma unroll
        for (int i = 0; i < 8; ++i) {
            float w = W[(size_t)(kb + i) * 128 + ncol];
            _Float16 hi, lo; splitf(w, hi, lo);
            hv[i] = hi; lv[i] = lo;
        }
        wHi[kc] = hv; wLo[kc] = lv;
    }
}

// accA += aH*bH ; accB += aH*bL + aL*bH   (true = accA + accB/2048)
__device__ __forceinline__ void mfma3(half8 aH, half8 aL, half8 bH, half8 bL,
                                      f32x4& accA, f32x4& accB)
{
    accA = __builtin_amdgcn_mfma_f32_16x16x32_f16(aH, bH, accA, 0, 0, 0);
    accB = __builtin_amdgcn_mfma_f32_16x16x32_f16(aH, bL, accB, 0, 0, 0);
    accB = __builtin_amdgcn_mfma_f32_16x16x32_f16(aL, bH, accB, 0, 0, 0);
}

// ---------------------------------------------------------------------------
// Kernel A: emb_proj = emb @ W_top, BW-targeted. 1024 blocks (4 waves/SIMD),
// register W-frags, direct global A-frags, LDS-bounce -> coalesced b128 stores.
// ---------------------------------------------------------------------------
__global__ __launch_bounds__(256) void emb_proj_mfma(
    const float* __restrict__ emb, const float* __restrict__ W_ih,
    float* __restrict__ emb_proj)
{
    __shared__ __align__(16) float bounce[16 * 132];
    const int t = threadIdx.x;
    const int w = t >> 6, lane = t & 63, g = lane >> 4, ln = lane & 15;

    half8 wHi[2][4], wLo[2][4];
    load_w4(W_ih, 32 * w + ln,      g, wHi[0], wLo[0]);
    load_w4(W_ih, 32 * w + 16 + ln, g, wHi[1], wLo[1]);

    for (int grp = blockIdx.x; grp < NGRP; grp += gridDim.x) {
        const int vb = grp * 16;
        int arow = vb + ln; if (arow >= VOCAB) arow = VOCAB - 1;
        const float* rp = emb + (size_t)arow * 128 + g * 8;
        half8 aHi[4], aLo[4];
#pragma unroll
        for (int kc = 0; kc < 4; ++kc) {
            float4 v0 = *(const float4*)(rp + kc * 32);
            float4 v1 = *(const float4*)(rp + kc * 32 + 4);
            float vv[8] = {v0.x, v0.y, v0.z, v0.w, v1.x, v1.y, v1.z, v1.w};
            half8 hv, lv;
#pragma unroll
            for (int i = 0; i < 8; ++i) {
                _Float16 hi, lo; splitf(vv[i], hi, lo);
                hv[i] = hi; lv[i] = lo;
            }
            aHi[kc] = hv; aLo[kc] = lv;
        }
        f32x4 accA[2], accB[2];
#pragma unroll
        for (int nt = 0; nt < 2; ++nt) {
            accA[nt] = {0.f, 0.f, 0.f, 0.f};
            accB[nt] = {0.f, 0.f, 0.f, 0.f};
        }
#pragma unroll
        for (int nt = 0; nt < 2; ++nt)
#pragma unroll
            for (int kc = 0; kc < 4; ++kc)
                mfma3(aHi[kc], aLo[kc], wHi[nt][kc], wLo[nt][kc],
                      accA[nt], accB[nt]);

        __syncthreads();                       // prev-iter bounce reads done
#pragma unroll
        for (int nt = 0; nt < 2; ++nt) {
            const int n = 32 * w + 16 * nt + ln;
#pragma unroll
            for (int r = 0; r < 4; ++r)
                bounce[(4 * g + r) * 132 + n] =
                    accA[nt][r] + accB[nt][r] * ISCL;
        }
        __syncthreads();
        const int r2 = t >> 4, c8 = (t & 15) * 8;
        const int vrow = vb + r2;
        if (vrow < VOCAB) {
            float4 o0 = *(const float4*)&bounce[r2 * 132 + c8];
            float4 o1 = *(const float4*)&bounce[r2 * 132 + c8 + 4];
            *(float4*)&emb_proj[(size_t)vrow * 128 + c8]     = o0;
            *(float4*)&emb_proj[(size_t)vrow * 128 + c8 + 4] = o1;
        }
    }
}

// ---------------------------------------------------------------------------
// Kernel B: persistent RNN. 256 blocks x 512 thr (8 waves = 2/SIMD), 16 rows.
// j-split-8: wave w owns j-tile [16w,16w+16), W^T frags resident (32 VGPR).
// h stored split hi/lo fp16 in XOR-swizzled LDS (row stride 256B == 0 mod
// banks; 16B granule q ^= row&7 -> conflict-free b128 reads).
// ---------------------------------------------------------------------------
__global__ __launch_bounds__(512) void rnn_mfma(
    const int* __restrict__ x, const int* __restrict__ tc,
    const float* __restrict__ tgt_emb,
    const float* __restrict__ W_ih, const float* __restrict__ W_hh,
    const float* __restrict__ b_ih, const float* __restrict__ b_hh,
    const float* __restrict__ W_cls, const float* __restrict__ b_cls,
    const float* __restrict__ ep, float* __restrict__ out)
{
    __shared__ _Float16 sHi[2][16 * 128];
    __shared__ _Float16 sLo[2][16 * 128];
    __shared__ int   xs[16 * 132];           // tokens [b][s], pad->0
    __shared__ float red[2][8][16];

    const int t = threadIdx.x;
    const int w = t >> 6, lane = t & 63, g = lane >> 4, ln = lane & 15;
    const int rb0 = blockIdx.x * 16;
    const int j0  = w * 16 + 4 * g;          // this lane's 4 output j's

    // ---- stage tokens (zero pad) ----
    for (int i = t; i < 16 * 132; i += 512) {
        int b = i / 132, s = i - b * 132;
        xs[i] = (s < 128) ? x[(size_t)(rb0 + b) * 128 + s] : 0;
    }
    // ---- stage tgt rows, split, swizzled into buf0 ----
    {
        const int b = t >> 5, k0 = (t & 31) * 4;
        const int tok = tc[rb0 + b];
        float4 v = *(const float4*)(tgt_emb + (size_t)tok * 128 + k0);
        float vv[4] = {v.x, v.y, v.z, v.w};
        half4 hv, lv;
#pragma unroll
        for (int i = 0; i < 4; ++i) {
            _Float16 hi, lo; splitf(vv[i], hi, lo);
            hv[i] = hi; lv[i] = lo;
        }
        const int a = b * 128 + (((k0 >> 3) ^ (b & 7)) << 3) + (k0 & 7);
        *(half4*)&sHi[0][a] = hv;
        *(half4*)&sLo[0][a] = lv;
    }
    __syncthreads();

    // ---- cc[j][b] = (tgt @ W_bot)^T + b_ih + b_hh ----
    half8 wHi[4], wLo[4];
    load_w4(W_ih + 128 * 128, w * 16 + ln, g, wHi, wLo);   // W_bot
    f32x4 cc;
    {
        half8 bH[4], bL[4];
#pragma unroll
        for (int kc = 0; kc < 4; ++kc) {
            const int a = ln * 128 + (((kc * 4 + g) ^ (ln & 7)) << 3);
            bH[kc] = *(const half8*)&sHi[0][a];
            bL[kc] = *(const half8*)&sLo[0][a];
        }
        float4 bi = *(const float4*)&b_ih[j0];
        float4 bh = *(const float4*)&b_hh[j0];
        f32x4 cA = {bi.x + bh.x, bi.y + bh.y, bi.z + bh.z, bi.w + bh.w};
        f32x4 cB = {0.f, 0.f, 0.f, 0.f};
#pragma unroll
        for (int kc = 0; kc < 4; ++kc)
            mfma3(wHi[kc], wLo[kc], bH[kc], bL[kc], cA, cB);
        cc = cA + cB * ISCL;
    }
    __syncthreads();                         // buf0 reads done
    // ---- zero buf0 (h_0 = 0) ----
    for (int i = t; i < 16 * 128; i += 512) {
        sHi[0][i] = (_Float16)0.f;
        sLo[0][i] = (_Float16)0.f;
    }

    // ---- W_hh^T frags, resident for all 128 steps ----
    load_w4(W_hh, w * 16 + ln, g, wHi, wLo);

    // ---- u_0 (32-bit voffset gather) ----
    int4 tk = *(const int4*)&xs[ln * 132];
    f32x4 uc;
    {
        unsigned uo = ((unsigned)tk.x << 7) + (unsigned)j0;
        float4 v = *(const float4*)(ep + uo);
        uc[0] = v.x; uc[1] = v.y; uc[2] = v.z; uc[3] = v.w;
    }
    __syncthreads();                         // buf0 zeroed

    // ---- 128-step recurrence, 1 barrier/step, unrolled x4 ----
#define RSTEP(CUR, NXT, TOKN) do {                                          \
    unsigned uo_ = ((unsigned)(TOKN) << 7) + (unsigned)j0;                  \
    float4 vn_ = *(const float4*)(ep + uo_);                                \
    half8 bH_[4], bL_[4];                                                   \
    _Pragma("unroll")                                                       \
    for (int kc = 0; kc < 4; ++kc) {                                        \
        const int a_ = ln * 128 + (((kc * 4 + g) ^ (ln & 7)) << 3);         \
        bH_[kc] = *(const half8*)&sHi[CUR][a_];                             \
        bL_[kc] = *(const half8*)&sLo[CUR][a_];                             \
    }                                                                       \
    f32x4 accA_ = cc + uc;                                                  \
    f32x4 accB_ = {0.f, 0.f, 0.f, 0.f};                                     \
    _Pragma("unroll")                                                       \
    for (int kc = 0; kc < 4; ++kc)                                          \
        mfma3(wHi[kc], wLo[kc], bH_[kc], bL_[kc], accA_, accB_);            \
    half4 hv_, lv_;                                                         \
    _Pragma("unroll")                                                       \
    for (int r = 0; r < 4; ++r) {                                           \
        float th_ = fast_tanh(accA_[r] + accB_[r] * ISCL);                  \
        _Float16 hi_, lo_; splitf(th_, hi_, lo_);                           \
        hv_[r] = hi_; lv_[r] = lo_;                                         \
    }                                                                       \
    {                                                                       \
        const int a_ = ln * 128 + (((j0 >> 3) ^ (ln & 7)) << 3) + (j0 & 7); \
        *(half4*)&sHi[NXT][a_] = hv_;                                       \
        *(half4*)&sLo[NXT][a_] = lv_;                                       \
    }                                                                       \
    __syncthreads();                                                        \
    uc[0] = vn_.x; uc[1] = vn_.y; uc[2] = vn_.z; uc[3] = vn_.w;             \
} while (0)

    for (int sb = 0; sb < 32; ++sb) {
        int4 tkn = *(const int4*)&xs[ln * 132 + 4 * (sb + 1)];  // sb=31 -> pad zeros
        RSTEP(0, 1, tk.y);
        RSTEP(1, 0, tk.z);
        RSTEP(0, 1, tk.w);
        RSTEP(1, 0, tkn.x);
        tk = tkn;
    }
#undef RSTEP
    // h_final in buf0

    // ---- logits^T = W_cls^T . h^T + b_cls ----
    load_w4(W_cls, w * 16 + ln, g, wHi, wLo);
    f32x4 L;
    {
        half8 bH[4], bL[4];
#pragma unroll
        for (int kc = 0; kc < 4; ++kc) {
            const int a = ln * 128 + (((kc * 4 + g) ^ (ln & 7)) << 3);
            bH[kc] = *(const half8*)&sHi[0][a];
            bL[kc] = *(const half8*)&sLo[0][a];
        }
        float4 bc = *(const float4*)&b_cls[j0];
        f32x4 lA = {bc.x, bc.y, bc.z, bc.w};
        f32x4 lB = {0.f, 0.f, 0.f, 0.f};
#pragma unroll
        for (int kc = 0; kc < 4; ++kc)
            mfma3(wHi[kc], wLo[kc], bH[kc], bL[kc], lA, lB);
        L = lA + lB * ISCL;
    }

    // ---- softmax over 128 classes per batch row b=ln (8-wave reduce) ----
    float mx = fmaxf(fmaxf(L[0], L[1]), fmaxf(L[2], L[3]));
    mx = fmaxf(mx, __shfl_xor(mx, 16, 64));
    mx = fmaxf(mx, __shfl_xor(mx, 32, 64));
    if (lane < 16) red[0][w][ln] = mx;
    __syncthreads();
    float gm = red[0][0][ln];
#pragma unroll
    for (int ww = 1; ww < 8; ++ww) gm = fmaxf(gm, red[0][ww][ln]);
    float sum = 0.f;
#pragma unroll
    for (int r = 0; r < 4; ++r) { L[r] = __expf(L[r] - gm); sum += L[r]; }
    sum += __shfl_xor(sum, 16, 64);
    sum += __shfl_xor(sum, 32, 64);
    if (lane < 16) red[1][w][ln] = sum;
    __syncthreads();
    float tot = 0.f;
#pragma unroll
    for (int ww = 0; ww < 8; ++ww) tot += red[1][ww][ln];
    const float inv = 1.0f / tot;
#pragma unroll
    for (int r = 0; r < 4; ++r)
        out[(size_t)(rb0 + ln) * 128 + j0 + r] = L[r] * inv;
}

// ---------------------------------------------------------------------------
extern "C" void kernel_launch(void* const* d_in, const int* in_sizes, int n_in,
                              void* d_out, int out_size, void* d_ws, size_t ws_size,
                              hipStream_t stream)
{
    const int*   x     = (const int*)d_in[0];
    const int*   tc    = (const int*)d_in[1];
    const float* emb   = (const float*)d_in[2];
    const float* tgt   = (const float*)d_in[3];
    const float* W_ih  = (const float*)d_in[4];
    const float* W_hh  = (const float*)d_in[5];
    const float* b_ih  = (const float*)d_in[6];
    const float* b_hh  = (const float*)d_in[7];
    const float* W_cls = (const float*)d_in[8];
    const float* b_cls = (const float*)d_in[9];
    float* out = (float*)d_out;
    float* emb_proj = (float*)d_ws;   // 50257*128 fp32 = 25.7 MB scratch

    emb_proj_mfma<<<1024, 256, 0, stream>>>(emb, W_ih, emb_proj);
    rnn_mfma<<<256, 512, 0, stream>>>(x, tc, tgt, W_ih, W_hh,
                                      b_ih, b_hh, W_cls, b_cls,
                                      emb_proj, out);
}

// Round 7
// 191.905 us; speedup vs baseline: 3.2777x; 1.1723x over previous
//
#include <hip/hip_runtime.h>

#define VOCAB 50257
#define NGRP  3142              // ceil(VOCAB/16)
#define SCL   2048.0f
#define ISCL  (1.0f / 2048.0f)

typedef _Float16 half8 __attribute__((ext_vector_type(8)));
typedef _Float16 half4 __attribute__((ext_vector_type(4)));
typedef float    f32x4 __attribute__((ext_vector_type(4)));

// LDS-only barrier: drains DS ops, leaves global loads (vmcnt) in flight.
// (__syncthreads() would emit s_waitcnt vmcnt(0) and serialize the u-gather
// latency into every step.)
#define LDS_BAR() asm volatile("s_waitcnt lgkmcnt(0)\n\ts_barrier" ::: "memory")

// fast tanh: 1 - 2/(e^{2x}+1)
__device__ __forceinline__ float fast_tanh(float x) {
    float e = __expf(2.0f * x);
    float r = __builtin_amdgcn_rcpf(e + 1.0f);
    return fmaf(-2.0f, r, 1.0f);
}
__device__ __forceinline__ void splitf(float v, _Float16& hi, _Float16& lo) {
    hi = (_Float16)v;
    lo = (_Float16)((v - (float)hi) * SCL);
}

// Fragment slice of a row-major [128][128] fp32 matrix: lane (g,ln) gets
// W[k = kc*32 + g*8 + i][ncol], split into hi / lo*2048 fp16.
__device__ __forceinline__ void load_w4(const float* __restrict__ W,
        int ncol, int g, half8 (&wHi)[4], half8 (&wLo)[4])
{
#pragma unroll
    for (int kc = 0; kc < 4; ++kc) {
        const int kb = kc * 32 + g * 8;
        half8 hv, lv;
#pragma unroll
        for (int i = 0; i < 8; ++i) {
            float w = W[(size_t)(kb + i) * 128 + ncol];
            _Float16 hi, lo; splitf(w, hi, lo);
            hv[i] = hi; lv[i] = lo;
        }
        wHi[kc] = hv; wLo[kc] = lv;
    }
}

// accA += aH*bH ; accB += aH*bL ; accC += aL*bH  (3 independent chains;
// true = accA + (accB+accC)/2048)
__device__ __forceinline__ void mfma3s(half8 aH, half8 aL, half8 bH, half8 bL,
                                       f32x4& accA, f32x4& accB, f32x4& accC)
{
    accA = __builtin_amdgcn_mfma_f32_16x16x32_f16(aH, bH, accA, 0, 0, 0);
    accB = __builtin_amdgcn_mfma_f32_16x16x32_f16(aH, bL, accB, 0, 0, 0);
    accC = __builtin_amdgcn_mfma_f32_16x16x32_f16(aL, bH, accC, 0, 0, 0);
}

// ---------------------------------------------------------------------------
// Kernel A: emb_proj = emb @ W_top (unchanged from round 6).
// ---------------------------------------------------------------------------
__global__ __launch_bounds__(256) void emb_proj_mfma(
    const float* __restrict__ emb, const float* __restrict__ W_ih,
    float* __restrict__ emb_proj)
{
    __shared__ __align__(16) float bounce[16 * 132];
    const int t = threadIdx.x;
    const int w = t >> 6, lane = t & 63, g = lane >> 4, ln = lane & 15;

    half8 wHi[2][4], wLo[2][4];
    load_w4(W_ih, 32 * w + ln,      g, wHi[0], wLo[0]);
    load_w4(W_ih, 32 * w + 16 + ln, g, wHi[1], wLo[1]);

    for (int grp = blockIdx.x; grp < NGRP; grp += gridDim.x) {
        const int vb = grp * 16;
        int arow = vb + ln; if (arow >= VOCAB) arow = VOCAB - 1;
        const float* rp = emb + (size_t)arow * 128 + g * 8;
        half8 aHi[4], aLo[4];
#pragma unroll
        for (int kc = 0; kc < 4; ++kc) {
            float4 v0 = *(const float4*)(rp + kc * 32);
            float4 v1 = *(const float4*)(rp + kc * 32 + 4);
            float vv[8] = {v0.x, v0.y, v0.z, v0.w, v1.x, v1.y, v1.z, v1.w};
            half8 hv, lv;
#pragma unroll
            for (int i = 0; i < 8; ++i) {
                _Float16 hi, lo; splitf(vv[i], hi, lo);
                hv[i] = hi; lv[i] = lo;
            }
            aHi[kc] = hv; aLo[kc] = lv;
        }
        f32x4 accA[2], accB[2], accC[2];
#pragma unroll
        for (int nt = 0; nt < 2; ++nt) {
            accA[nt] = {0.f, 0.f, 0.f, 0.f};
            accB[nt] = {0.f, 0.f, 0.f, 0.f};
            accC[nt] = {0.f, 0.f, 0.f, 0.f};
        }
#pragma unroll
        for (int nt = 0; nt < 2; ++nt)
#pragma unroll
            for (int kc = 0; kc < 4; ++kc)
                mfma3s(aHi[kc], aLo[kc], wHi[nt][kc], wLo[nt][kc],
                       accA[nt], accB[nt], accC[nt]);

        __syncthreads();                       // prev-iter bounce reads done
#pragma unroll
        for (int nt = 0; nt < 2; ++nt) {
            const int n = 32 * w + 16 * nt + ln;
#pragma unroll
            for (int r = 0; r < 4; ++r)
                bounce[(4 * g + r) * 132 + n] =
                    accA[nt][r] + (accB[nt][r] + accC[nt][r]) * ISCL;
        }
        __syncthreads();
        const int r2 = t >> 4, c8 = (t & 15) * 8;
        const int vrow = vb + r2;
        if (vrow < VOCAB) {
            float4 o0 = *(const float4*)&bounce[r2 * 132 + c8];
            float4 o1 = *(const float4*)&bounce[r2 * 132 + c8 + 4];
            *(float4*)&emb_proj[(size_t)vrow * 128 + c8]     = o0;
            *(float4*)&emb_proj[(size_t)vrow * 128 + c8 + 4] = o1;
        }
    }
}

// ---------------------------------------------------------------------------
// Kernel B: persistent RNN. 256 blocks x 512 thr (8 waves), 16 rows/block.
// Step loop: LDS-only barrier (global gathers stay in flight) + 2-deep
// u-prefetch pipeline + 3 independent MFMA accumulation chains.
// ---------------------------------------------------------------------------
__global__ __launch_bounds__(512) void rnn_mfma(
    const int* __restrict__ x, const int* __restrict__ tc,
    const float* __restrict__ tgt_emb,
    const float* __restrict__ W_ih, const float* __restrict__ W_hh,
    const float* __restrict__ b_ih, const float* __restrict__ b_hh,
    const float* __restrict__ W_cls, const float* __restrict__ b_cls,
    const float* __restrict__ ep, float* __restrict__ out)
{
    __shared__ _Float16 sHi[2][16 * 128];
    __shared__ _Float16 sLo[2][16 * 128];
    __shared__ int   xs[16 * 132];           // tokens [b][s], pad->0
    __shared__ float red[2][8][16];

    const int t = threadIdx.x;
    const int w = t >> 6, lane = t & 63, g = lane >> 4, ln = lane & 15;
    const int rb0 = blockIdx.x * 16;
    const int j0  = w * 16 + 4 * g;          // this lane's 4 output j's

    // ---- stage tokens (zero pad) ----
    for (int i = t; i < 16 * 132; i += 512) {
        int b = i / 132, s = i - b * 132;
        xs[i] = (s < 128) ? x[(size_t)(rb0 + b) * 128 + s] : 0;
    }
    // ---- stage tgt rows, split, swizzled into buf0 ----
    {
        const int b = t >> 5, k0 = (t & 31) * 4;
        const int tok = tc[rb0 + b];
        float4 v = *(const float4*)(tgt_emb + (size_t)tok * 128 + k0);
        float vv[4] = {v.x, v.y, v.z, v.w};
        half4 hv, lv;
#pragma unroll
        for (int i = 0; i < 4; ++i) {
            _Float16 hi, lo; splitf(vv[i], hi, lo);
            hv[i] = hi; lv[i] = lo;
        }
        const int a = b * 128 + (((k0 >> 3) ^ (b & 7)) << 3) + (k0 & 7);
        *(half4*)&sHi[0][a] = hv;
        *(half4*)&sLo[0][a] = lv;
    }
    __syncthreads();

    // ---- cc[j][b] = (tgt @ W_bot)^T + b_ih + b_hh ----
    half8 wHi[4], wLo[4];
    load_w4(W_ih + 128 * 128, w * 16 + ln, g, wHi, wLo);   // W_bot
    f32x4 cc;
    {
        half8 bH[4], bL[4];
#pragma unroll
        for (int kc = 0; kc < 4; ++kc) {
            const int a = ln * 128 + (((kc * 4 + g) ^ (ln & 7)) << 3);
            bH[kc] = *(const half8*)&sHi[0][a];
            bL[kc] = *(const half8*)&sLo[0][a];
        }
        float4 bi = *(const float4*)&b_ih[j0];
        float4 bh = *(const float4*)&b_hh[j0];
        f32x4 cA = {bi.x + bh.x, bi.y + bh.y, bi.z + bh.z, bi.w + bh.w};
        f32x4 cB = {0.f, 0.f, 0.f, 0.f};
        f32x4 cC = {0.f, 0.f, 0.f, 0.f};
#pragma unroll
        for (int kc = 0; kc < 4; ++kc)
            mfma3s(wHi[kc], wLo[kc], bH[kc], bL[kc], cA, cB, cC);
        cc = cA + (cB + cC) * ISCL;
    }
    __syncthreads();                         // buf0 reads done
    // ---- zero buf0 (h_0 = 0) ----
    for (int i = t; i < 16 * 128; i += 512) {
        sHi[0][i] = (_Float16)0.f;
        sLo[0][i] = (_Float16)0.f;
    }

    // ---- W_hh^T frags, resident for all 128 steps ----
    load_w4(W_hh, w * 16 + ln, g, wHi, wLo);

    // ---- u pipeline: uc0 = u(s), uc1 = u(s+1) ----
    int4 tk = *(const int4*)&xs[ln * 132];
    f32x4 uc0, uc1;
    {
        unsigned a0 = ((unsigned)tk.x << 7) + (unsigned)j0;
        unsigned a1 = ((unsigned)tk.y << 7) + (unsigned)j0;
        float4 v0 = *(const float4*)(ep + a0);
        float4 v1 = *(const float4*)(ep + a1);
        uc0[0] = v0.x; uc0[1] = v0.y; uc0[2] = v0.z; uc0[3] = v0.w;
        uc1[0] = v1.x; uc1[1] = v1.y; uc1[2] = v1.z; uc1[3] = v1.w;
    }
    __syncthreads();                         // buf0 zeroed

    // ---- 128-step recurrence: LDS-only barrier, 2-deep u pipeline ----
#define RSTEP(CUR, NXT, TOK2) do {                                          \
    unsigned uo_ = ((unsigned)(TOK2) << 7) + (unsigned)j0;                  \
    float4 v2_ = *(const float4*)(ep + uo_);      /* u(s+2), async */       \
    half8 bH_[4], bL_[4];                                                   \
    _Pragma("unroll")                                                       \
    for (int kc = 0; kc < 4; ++kc) {                                        \
        const int a_ = ln * 128 + (((kc * 4 + g) ^ (ln & 7)) << 3);         \
        bH_[kc] = *(const half8*)&sHi[CUR][a_];                             \
        bL_[kc] = *(const half8*)&sLo[CUR][a_];                             \
    }                                                                       \
    f32x4 accA_ = cc + uc0;                                                 \
    f32x4 accB_ = {0.f, 0.f, 0.f, 0.f};                                     \
    f32x4 accC_ = {0.f, 0.f, 0.f, 0.f};                                     \
    _Pragma("unroll")                                                       \
    for (int kc = 0; kc < 4; ++kc)                                          \
        mfma3s(wHi[kc], wLo[kc], bH_[kc], bL_[kc], accA_, accB_, accC_);    \
    half4 hv_, lv_;                                                         \
    _Pragma("unroll")                                                       \
    for (int r = 0; r < 4; ++r) {                                           \
        float th_ = fast_tanh(accA_[r] + (accB_[r] + accC_[r]) * ISCL);     \
        _Float16 hi_, lo_; splitf(th_, hi_, lo_);                           \
        hv_[r] = hi_; lv_[r] = lo_;                                         \
    }                                                                       \
    {                                                                       \
        const int a_ = ln * 128 + (((j0 >> 3) ^ (ln & 7)) << 3) + (j0 & 7); \
        *(half4*)&sHi[NXT][a_] = hv_;                                       \
        *(half4*)&sLo[NXT][a_] = lv_;                                       \
    }                                                                       \
    LDS_BAR();                                                              \
    uc0 = uc1;                                                              \
    uc1[0] = v2_.x; uc1[1] = v2_.y; uc1[2] = v2_.z; uc1[3] = v2_.w;         \
} while (0)

    for (int sb = 0; sb < 32; ++sb) {
        int4 tkn = *(const int4*)&xs[ln * 132 + 4 * (sb + 1)];  // next quad (sb=31 -> pad zeros)
        RSTEP(0, 1, tk.z);    // s=4sb+0, u(s+2)=tok[4sb+2]
        RSTEP(1, 0, tk.w);    // s=4sb+1, u(s+2)=tok[4sb+3]
        RSTEP(0, 1, tkn.x);   // s=4sb+2, u(s+2)=tok[4sb+4]
        RSTEP(1, 0, tkn.y);   // s=4sb+3, u(s+2)=tok[4sb+5]
        tk = tkn;
    }
#undef RSTEP
    // h_final in buf0 (last write was NXT=0, visible after LDS_BAR)

    // ---- logits^T = W_cls^T . h^T + b_cls ----
    load_w4(W_cls, w * 16 + ln, g, wHi, wLo);
    f32x4 L;
    {
        half8 bH[4], bL[4];
#pragma unroll
        for (int kc = 0; kc < 4; ++kc) {
            const int a = ln * 128 + (((kc * 4 + g) ^ (ln & 7)) << 3);
            bH[kc] = *(const half8*)&sHi[0][a];
            bL[kc] = *(const half8*)&sLo[0][a];
        }
        float4 bc = *(const float4*)&b_cls[j0];
        f32x4 lA = {bc.x, bc.y, bc.z, bc.w};
        f32x4 lB = {0.f, 0.f, 0.f, 0.f};
        f32x4 lC = {0.f, 0.f, 0.f, 0.f};
#pragma unroll
        for (int kc = 0; kc < 4; ++kc)
            mfma3s(wHi[kc], wLo[kc], bH[kc], bL[kc], lA, lB, lC);
        L = lA + (lB + lC) * ISCL;
    }

    // ---- softmax over 128 classes per batch row b=ln (8-wave reduce) ----
    float mx = fmaxf(fmaxf(L[0], L[1]), fmaxf(L[2], L[3]));
    mx = fmaxf(mx, __shfl_xor(mx, 16, 64));
    mx = fmaxf(mx, __shfl_xor(mx, 32, 64));
    if (lane < 16) red[0][w][ln] = mx;
    __syncthreads();
    float gm = red[0][0][ln];
#pragma unroll
    for (int ww = 1; ww < 8; ++ww) gm = fmaxf(gm, red[0][ww][ln]);
    float sum = 0.f;
#pragma unroll
    for (int r = 0; r < 4; ++r) { L[r] = __expf(L[r] - gm); sum += L[r]; }
    sum += __shfl_xor(sum, 16, 64);
    sum += __shfl_xor(sum, 32, 64);
    if (lane < 16) red[1][w][ln] = sum;
    __syncthreads();
    float tot = 0.f;
#pragma unroll
    for (int ww = 0; ww < 8; ++ww) tot += red[1][ww][ln];
    const float inv = 1.0f / tot;
#pragma unroll
    for (int r = 0; r < 4; ++r)
        out[(size_t)(rb0 + ln) * 128 + j0 + r] = L[r] * inv;
}

// ---------------------------------------------------------------------------
extern "C" void kernel_launch(void* const* d_in, const int* in_sizes, int n_in,
                              void* d_out, int out_size, void* d_ws, size_t ws_size,
                              hipStream_t stream)
{
    const int*   x     = (const int*)d_in[0];
    const int*   tc    = (const int*)d_in[1];
    const float* emb   = (const float*)d_in[2];
    const float* tgt   = (const float*)d_in[3];
    const float* W_ih  = (const float*)d_in[4];
    const float* W_hh  = (const float*)d_in[5];
    const float* b_ih  = (const float*)d_in[6];
    const float* b_hh  = (const float*)d_in[7];
    const float* W_cls = (const float*)d_in[8];
    const float* b_cls = (const float*)d_in[9];
    float* out = (float*)d_out;
    float* emb_proj = (float*)d_ws;   // 50257*128 fp32 = 25.7 MB scratch

    emb_proj_mfma<<<1024, 256, 0, stream>>>(emb, W_ih, emb_proj);
    rnn_mfma<<<256, 512, 0, stream>>>(x, tc, tgt, W_ih, W_hh,
                                      b_ih, b_hh, W_cls, b_cls,
                                      emb_proj, out);
}